// Round 3
// baseline (200.134 us; speedup 1.0000x reference)
//
#include <hip/hip_runtime.h>

// GaussianKernelRegression == flash attention:
//   s[n,m] = (q_n . t_m - 0.5*|t_m|^2) / std_n^2  (q^2 drops in softmax)
//   out = softmax_m(s) @ source_db
// V5: LDS-traffic-focused restructure (round-2 evidence: LDS-port-bound).
//  - 512-thr blocks = 8 waves = 4 qg x 2 p(m-half). BQ=128, BM=32.
//  - 2 Q-frags per wave: every T A-read feeds 2 MFMAs (halves QK LDS traffic).
//  - PV swapped: O^T = V^T * P via mfma_f32_16x16x16f16 with P as B-operand
//    DIRECTLY from registers (s-values are already in B-frag layout). No P
//    pack to LDS, no second mid-tile barrier, no lsum/cf exchange. Each wave
//    accumulates partial-O over its own m-half; p-pair partials summed once
//    in the epilogue through LDS.
//  - V pre-packed as paired 16x16x16 A-frag blobs -> b128 reads.
//  - Exact-skip rescale: skip the 128-mul O rescale when no lane's max grew.
// fp16 hi/lo split of T for QK precision (validated rounds 1-2, absmax .047).

#define N_Q 4096
#define M_DB 16384
#define D_K 256
#define BQ 128
#define BM 32
#define NCHUNK 8
#define MC (M_DB / NCHUNK)   // 2048
#define NTILE (MC / BM)      // 64
#define NCH 8                // k-chunks of 32
#define LOG2E 1.44269504088896f

typedef _Float16 f16;
typedef _Float16 f16x4v __attribute__((ext_vector_type(4)));
typedef _Float16 f16x8 __attribute__((ext_vector_type(8)));
typedef float f32x4 __attribute__((ext_vector_type(4)));
typedef unsigned short u16;

typedef const __attribute__((address_space(1))) void cg_void;
typedef __attribute__((address_space(3))) void lds_void;

__device__ __forceinline__ void gload16(const void* g, void* s) {
  __builtin_amdgcn_global_load_lds((cg_void*)g, (lds_void*)s, 16, 0, 0);
}

// ---------- prep: Q fragment blobs. blob qt: slot=c*64+l, lane l elem e -> Q[qt*16+(l&15)][c*32+((l>>4)&3)*8+e]
__global__ void k_prep_q(const float* __restrict__ q, u16* __restrict__ qpk) {
  int qt = blockIdx.x;
  int t = threadIdx.x;
#pragma unroll
  for (int i = 0; i < 2; i++) {
    int slot = t + 256 * i;
    int c = slot >> 6, l = slot & 63;
    int row = qt * 16 + (l & 15);
    int k0 = c * 32 + ((l >> 4) & 3) * 8;
    const float* src = q + (size_t)row * D_K + k0;
    f16x8 o;
#pragma unroll
    for (int e = 0; e < 8; e++) o[e] = (f16)src[e];
    *(f16x8*)(qpk + (size_t)qt * 4096 + slot * 8) = o;
  }
}

// ---------- prep: 0.5 * row-sum-sq of target_db
__global__ void k_prep_tq(const float* __restrict__ tdb, float* __restrict__ tq) {
  int t = threadIdx.x;
  int row = blockIdx.x * 8 + (t >> 5);
  int ln = t & 31;
  float s = 0.f;
#pragma unroll
  for (int i = 0; i < 8; i++) { float x = tdb[(size_t)row * D_K + ln + 32 * i]; s += x * x; }
#pragma unroll
  for (int off = 16; off >= 1; off >>= 1) s += __shfl_xor(s, off);
  if (ln == 0) tq[row] = 0.5f * s;
}

// ---------- prep: T fragment blobs (hi/lo fp16 split). chunk = p*1024 + c*128 + hl*64 + l
__global__ void k_prep_t(const float* __restrict__ tdb, u16* __restrict__ pkT) {
  int ti = blockIdx.x;
  int t = threadIdx.x;
#pragma unroll
  for (int i = 0; i < 8; i++) {
    int ck = t + 256 * i;
    int l = ck & 63, hl = (ck >> 6) & 1, c = (ck >> 7) & 7, p = (ck >> 10) & 1;
    int row = ti * 32 + p * 16 + (l & 15);
    int k0 = c * 32 + ((l >> 4) & 3) * 8;
    const float* src = tdb + (size_t)row * D_K + k0;
    f16x8 o;
#pragma unroll
    for (int e = 0; e < 8; e++) {
      float v = src[e];
      f16 h = (f16)v;
      o[e] = hl ? (f16)(v - (float)h) : h;
    }
    *(f16x8*)(pkT + (size_t)ti * 16384 + ck * 8) = o;   // 32KB per tile
  }
}

// ---------- prep: V^T paired A-frag blobs (16x16x16). slot = p*512 + c*64 + l:
// lane l elem e -> V[ti*32 + p*16 + ((l>>4)&3)*4 + (e&3)][c*32 + (e>>2)*16 + (l&15)]
__global__ void k_prep_v(const float* __restrict__ src, u16* __restrict__ pkV) {
  int ti = blockIdx.x;   // M_DB/32 tiles
  int t = threadIdx.x;   // 256
#pragma unroll
  for (int i = 0; i < 4; i++) {
    int slot = t + 256 * i;
    int l = slot & 63, c = (slot >> 6) & 7, p = slot >> 9;
    int mbase = ti * 32 + p * 16 + ((l >> 4) & 3) * 4;
    int dbase = c * 32 + (l & 15);
    f16x8 o;
#pragma unroll
    for (int e = 0; e < 8; e++)
      o[e] = (f16)src[(size_t)(mbase + (e & 3)) * D_K + dbase + (e >> 2) * 16];
    *(f16x8*)(pkV + (size_t)ti * 8192 + slot * 8) = o;   // 16KB per tile
  }
}

// ---------- main flash kernel ----------
__launch_bounds__(512, 2)
__global__ void k_main(const u16* __restrict__ qpk, const u16* __restrict__ pkT,
                       const u16* __restrict__ pkV, const float* __restrict__ tq,
                       const float* __restrict__ stdv,
                       float* __restrict__ pO, float* __restrict__ pm, float* __restrict__ pl)
{
  __shared__ __align__(16) char su[2][49152];   // [T 32KB | V^T 16KB] double-buffered
  __shared__ float s_pmax[4][2][2][16];
  __shared__ float s_lred[4][2][16];
  __shared__ __align__(16) float s_tq[2][32];

  const int bid = blockIdx.x, chunk = bid & 7, qblk = bid >> 3;
  const int tid = threadIdx.x;
  const int w = tid >> 6, l = tid & 63;
  const int qg = w >> 1, p = w & 1;
  const int lq = l & 15, mg = (l >> 4) & 3;

  float is2l[2];
#pragma unroll
  for (int f = 0; f < 2; f++) {
    float sd = stdv[qblk * BQ + f * 64 + qg * 16 + lq];
    is2l[f] = LOG2E / (sd * sd);
  }

  // 2 Q fragment sets in registers (64 VGPRs)
  f16x8 qf[2][NCH];
#pragma unroll
  for (int f = 0; f < 2; f++) {
    const u16* qb = qpk + (size_t)(qblk * 8 + f * 4 + qg) * 4096 + l * 8;
#pragma unroll
    for (int c = 0; c < NCH; c++) qf[f][c] = *(const f16x8*)(qb + c * 512);
  }

  f32x4 acc[2][16];   // O^T partials: [qfrag][d-chunk], lane: col=q(l&15), row=d mg*4+r
#pragma unroll
  for (int f = 0; f < 2; f++)
#pragma unroll
    for (int dc = 0; dc < 16; dc++) acc[f][dc] = (f32x4){0.f, 0.f, 0.f, 0.f};
  float mrun[2] = {-3.0e38f, -3.0e38f}, lrun[2] = {0.f, 0.f};

  const size_t tbase = (size_t)chunk * NTILE;

  // prologue: stage tile 0
  {
    const char* gT = (const char*)pkT + tbase * 32768;
    const char* gV = (const char*)pkV + tbase * 16384;
    char* sb = &su[0][0];
#pragma unroll
    for (int i = 0; i < 4; i++) gload16(gT + i * 8192 + tid * 16, sb + i * 8192 + w * 1024);
#pragma unroll
    for (int i = 0; i < 2; i++) gload16(gV + i * 8192 + tid * 16, sb + 32768 + i * 8192 + w * 1024);
    if (tid < 32) s_tq[0][tid] = tq[chunk * MC + tid];
  }
  __syncthreads();

  for (int t = 0; t < NTILE; ++t) {
    const int cur = t & 1, nxt = cur ^ 1;
    const bool hasNext = (t + 1 < NTILE);
    float tqv = 0.f;
    if (hasNext) {   // issue next-tile staging; drained at end-of-tile syncthreads
      const char* gT = (const char*)pkT + (tbase + t + 1) * 32768;
      const char* gV = (const char*)pkV + (tbase + t + 1) * 16384;
      char* sb = &su[nxt][0];
#pragma unroll
      for (int i = 0; i < 4; i++) gload16(gT + i * 8192 + tid * 16, sb + i * 8192 + w * 1024);
#pragma unroll
      for (int i = 0; i < 2; i++) gload16(gV + i * 8192 + tid * 16, sb + 32768 + i * 8192 + w * 1024);
      if (tid < 32) tqv = tq[chunk * MC + (t + 1) * BM + tid];
    }

    // ---- QK^T swapped: A=T (own m-half), B=Q regs -> D[m][q]; 2 q-frags per A-read ----
    f32x4 s0 = {0.f, 0.f, 0.f, 0.f}, s1 = {0.f, 0.f, 0.f, 0.f};
    const char* tb = &su[cur][0] + p * 16384 + l * 16;
#pragma unroll
    for (int c = 0; c < NCH; c++) {
      f16x8 aH = *(const f16x8*)(tb + c * 2048);
      f16x8 aL = *(const f16x8*)(tb + c * 2048 + 1024);
      s0 = __builtin_amdgcn_mfma_f32_16x16x32_f16(aH, qf[0][c], s0, 0, 0, 0);
      s1 = __builtin_amdgcn_mfma_f32_16x16x32_f16(aH, qf[1][c], s1, 0, 0, 0);
      s0 = __builtin_amdgcn_mfma_f32_16x16x32_f16(aL, qf[0][c], s0, 0, 0, 0);
      s1 = __builtin_amdgcn_mfma_f32_16x16x32_f16(aL, qf[1][c], s1, 0, 0, 0);
    }
    const f32x4 t4 = *(const f32x4*)&s_tq[cur][p * 16 + mg * 4];
    float l20[4], l21[4];
#pragma unroll
    for (int r = 0; r < 4; r++) {
      l20[r] = (s0[r] - t4[r]) * is2l[0];
      l21[r] = (s1[r] - t4[r]) * is2l[1];
    }
    float px0 = fmaxf(fmaxf(l20[0], l20[1]), fmaxf(l20[2], l20[3]));
    float px1 = fmaxf(fmaxf(l21[0], l21[1]), fmaxf(l21[2], l21[3]));
    px0 = fmaxf(px0, __shfl_xor(px0, 16)); px0 = fmaxf(px0, __shfl_xor(px0, 32));
    px1 = fmaxf(px1, __shfl_xor(px1, 16)); px1 = fmaxf(px1, __shfl_xor(px1, 32));
    if (l < 16) { s_pmax[qg][p][0][l] = px0; s_pmax[qg][p][1][l] = px1; }

    // B1: raw barrier (staged loads stay in flight)
    asm volatile("s_waitcnt lgkmcnt(0)" ::: "memory");
    __builtin_amdgcn_s_barrier();
    asm volatile("" ::: "memory");

    const float mnew0 = fmaxf(mrun[0], fmaxf(s_pmax[qg][0][0][lq], s_pmax[qg][1][0][lq]));
    const float mnew1 = fmaxf(mrun[1], fmaxf(s_pmax[qg][0][1][lq], s_pmax[qg][1][1][lq]));
    if (__any((mnew0 > mrun[0]) | (mnew1 > mrun[1]))) {   // exact-skip rescale
      const float cl0 = exp2f(mrun[0] - mnew0);
      const float cl1 = exp2f(mrun[1] - mnew1);
      mrun[0] = mnew0; mrun[1] = mnew1;
      lrun[0] *= cl0;  lrun[1] *= cl1;
#pragma unroll
      for (int dc = 0; dc < 16; dc++) {
#pragma unroll
        for (int r = 0; r < 4; r++) { acc[0][dc][r] *= cl0; acc[1][dc][r] *= cl1; }
      }
    }
    float pr0[4], pr1[4], ls0 = 0.f, ls1 = 0.f;
#pragma unroll
    for (int r = 0; r < 4; r++) {
      pr0[r] = exp2f(l20[r] - mrun[0]); ls0 += pr0[r];
      pr1[r] = exp2f(l21[r] - mrun[1]); ls1 += pr1[r];
    }
    ls0 += __shfl_xor(ls0, 16); ls0 += __shfl_xor(ls0, 32);
    ls1 += __shfl_xor(ls1, 16); ls1 += __shfl_xor(ls1, 32);
    lrun[0] += ls0; lrun[1] += ls1;

    // P as B-operand fragments, straight from registers (k = own m-half)
    f16x4v pf0, pf1;
#pragma unroll
    for (int r = 0; r < 4; r++) { pf0[r] = (f16)pr0[r]; pf1[r] = (f16)pr1[r]; }

    // ---- PV swapped: acc[f][dc] += V^T_frag(dc) * pf[f], K=16 (own m-half) ----
    const char* vb = &su[cur][0] + 32768 + p * 8192 + l * 16;
#pragma unroll
    for (int c = 0; c < 8; c++) {
      f16x8 vv = *(const f16x8*)(vb + c * 1024);
      f16x4v a0 = __builtin_shufflevector(vv, vv, 0, 1, 2, 3);
      f16x4v a1 = __builtin_shufflevector(vv, vv, 4, 5, 6, 7);
      acc[0][2 * c]     = __builtin_amdgcn_mfma_f32_16x16x16f16(a0, pf0, acc[0][2 * c], 0, 0, 0);
      acc[1][2 * c]     = __builtin_amdgcn_mfma_f32_16x16x16f16(a0, pf1, acc[1][2 * c], 0, 0, 0);
      acc[0][2 * c + 1] = __builtin_amdgcn_mfma_f32_16x16x16f16(a1, pf0, acc[0][2 * c + 1], 0, 0, 0);
      acc[1][2 * c + 1] = __builtin_amdgcn_mfma_f32_16x16x16f16(a1, pf1, acc[1][2 * c + 1], 0, 0, 0);
    }
    if (hasNext && tid < 32) s_tq[nxt][tid] = tqv;
    __syncthreads();   // drains vmcnt: next tile staged + sync stats buffers
  }

  // ---- epilogue: sum p-pair partials via LDS, store per-chunk partials ----
  if (p == 1 && l < 16) { s_lred[qg][0][l] = lrun[0]; s_lred[qg][1][l] = lrun[1]; }
  char* red = (char*)&su[0][0] + qg * 16384;
#pragma unroll
  for (int f = 0; f < 2; f++) {
    if (p == 1) {
#pragma unroll
      for (int dc = 0; dc < 16; dc++) *(f32x4*)(red + dc * 1024 + l * 16) = acc[f][dc];
    }
    __syncthreads();
    if (p == 0) {
#pragma unroll
      for (int dc = 0; dc < 16; dc++) {
        f32x4 o = *(const f32x4*)(red + dc * 1024 + l * 16);
#pragma unroll
        for (int r = 0; r < 4; r++) acc[f][dc][r] += o[r];
      }
      const int row = qblk * BQ + f * 64 + qg * 16 + lq;
#pragma unroll
      for (int dc = 0; dc < 16; dc++) {
#pragma unroll
        for (int r = 0; r < 4; r++)
          pO[((size_t)chunk * N_Q + row) * D_K + dc * 16 + mg * 4 + r] = acc[f][dc][r];
      }
      if (l < 16) {
        pm[(size_t)chunk * N_Q + row] = mrun[f];
        pl[(size_t)chunk * N_Q + row] = lrun[f] + s_lred[qg][f][lq];
      }
    }
    __syncthreads();
  }
}

// ---------- combine chunk partials ----------
__global__ void k_combine(const float* __restrict__ pO, const float* __restrict__ pm,
                          const float* __restrict__ pl, float* __restrict__ out)
{
  int n = blockIdx.x, d = threadIdx.x;
  float M = -3.0e38f;
#pragma unroll
  for (int c = 0; c < NCHUNK; c++) M = fmaxf(M, pm[(size_t)c * N_Q + n]);
  float den = 0.f, num = 0.f;
#pragma unroll
  for (int c = 0; c < NCHUNK; c++) {
    float w = exp2f(pm[(size_t)c * N_Q + n] - M);
    den += w * pl[(size_t)c * N_Q + n];
    num += w * pO[((size_t)c * N_Q + n) * D_K + d];
  }
  out[(size_t)n * D_K + d] = num / den;
}

extern "C" void kernel_launch(void* const* d_in, const int* in_sizes, int n_in,
                              void* d_out, int out_size, void* d_ws, size_t ws_size,
                              hipStream_t stream)
{
  const float* q    = (const float*)d_in[0];
  const float* stdv = (const float*)d_in[1];
  const float* src  = (const float*)d_in[2];   // source_db (V)
  const float* tdb  = (const float*)d_in[3];   // target_db (T)
  float* out = (float*)d_out;

  char* wsp = (char*)d_ws;
  u16* qpk = (u16*)wsp;   wsp += (size_t)N_Q * D_K * 2;            // 2 MB
  u16* pkT = (u16*)wsp;   wsp += (size_t)M_DB * D_K * 2 * 2;       // 16.8 MB (hi+lo)
  u16* pkV = (u16*)wsp;   wsp += (size_t)M_DB * D_K * 2;           // 8.4 MB
  float* tq = (float*)wsp; wsp += (size_t)M_DB * 4;                // 64 KB
  float* pO = (float*)wsp; wsp += (size_t)NCHUNK * N_Q * D_K * 4;  // 33.5 MB
  float* pm = (float*)wsp; wsp += (size_t)NCHUNK * N_Q * 4;
  float* pl = (float*)wsp; wsp += (size_t)NCHUNK * N_Q * 4;

  hipLaunchKernelGGL(k_prep_q,  dim3(N_Q / 16), dim3(256), 0, stream, q, qpk);
  hipLaunchKernelGGL(k_prep_tq, dim3(M_DB / 8), dim3(256), 0, stream, tdb, tq);
  hipLaunchKernelGGL(k_prep_t,  dim3(M_DB / 32), dim3(256), 0, stream, tdb, pkT);
  hipLaunchKernelGGL(k_prep_v,  dim3(M_DB / 32), dim3(256), 0, stream, src, pkV);
  hipLaunchKernelGGL(k_main,    dim3(32 * NCHUNK), dim3(512), 0, stream,
                     qpk, pkT, pkV, tq, stdv, pO, pm, pl);
  hipLaunchKernelGGL(k_combine, dim3(N_Q), dim3(256), 0, stream, pO, pm, pl, out);
}

// Round 4
// 177.838 us; speedup vs baseline: 1.1254x; 1.1254x over previous
//
#include <hip/hip_runtime.h>

// GaussianKernelRegression == flash attention:
//   s[n,m] = (q_n . t_m - 0.5*|t_m|^2) / std_n^2  (q^2 drops in softmax)
//   out = softmax_m(s) @ source_db
// V6: de-serialization (rounds 1-3 evidence: time pinned ~171-186us across
// occupancy/conflict/traffic changes => serial phase chain is the binder).
//  - Each wave's m-half is its OWN flash-decode chunk (16 effective chunks):
//    softmax fully in-register (4-reg max + 2 shfl_xor), NO mid-tile barrier,
//    no stat LDS exchange, no epilogue cross-wave reduce.
//  - ONE barrier per tile; triple-buffered staging, counted s_waitcnt vmcnt(6)
//    (never drains the prefetch queue in the main loop).
//  - 4 independent QK MFMA chains (hi/lo x 2 q-frags); s_setprio around MFMA.
//  - Partials stored f16 (ws stays ~61MB at 16 chunks).
// fp16 hi/lo split of T for QK precision (validated r1-r3, absmax .047).

#define N_Q 4096
#define M_DB 16384
#define D_K 256
#define BQ 128
#define BM 32
#define NCHUNK 8
#define NCHE (NCHUNK * 2)    // effective chunks (p-halves independent)
#define MC (M_DB / NCHUNK)   // 2048
#define NTILE (MC / BM)      // 64
#define NCH 8                // k-chunks of 32
#define LOG2E 1.44269504088896f

typedef _Float16 f16;
typedef _Float16 f16x4v __attribute__((ext_vector_type(4)));
typedef _Float16 f16x8 __attribute__((ext_vector_type(8)));
typedef float f32x4 __attribute__((ext_vector_type(4)));
typedef unsigned short u16;

typedef const __attribute__((address_space(1))) void cg_void;
typedef __attribute__((address_space(3))) void lds_void;

__device__ __forceinline__ void gload16(const void* g, void* s) {
  __builtin_amdgcn_global_load_lds((cg_void*)g, (lds_void*)s, 16, 0, 0);
}

// ---------- prep: Q fragment blobs. blob qt: slot=c*64+l, lane l elem e -> Q[qt*16+(l&15)][c*32+((l>>4)&3)*8+e]
__global__ void k_prep_q(const float* __restrict__ q, u16* __restrict__ qpk) {
  int qt = blockIdx.x;
  int t = threadIdx.x;
#pragma unroll
  for (int i = 0; i < 2; i++) {
    int slot = t + 256 * i;
    int c = slot >> 6, l = slot & 63;
    int row = qt * 16 + (l & 15);
    int k0 = c * 32 + ((l >> 4) & 3) * 8;
    const float* src = q + (size_t)row * D_K + k0;
    f16x8 o;
#pragma unroll
    for (int e = 0; e < 8; e++) o[e] = (f16)src[e];
    *(f16x8*)(qpk + (size_t)qt * 4096 + slot * 8) = o;
  }
}

// ---------- prep: 0.5 * row-sum-sq of target_db
__global__ void k_prep_tq(const float* __restrict__ tdb, float* __restrict__ tq) {
  int t = threadIdx.x;
  int row = blockIdx.x * 8 + (t >> 5);
  int ln = t & 31;
  float s = 0.f;
#pragma unroll
  for (int i = 0; i < 8; i++) { float x = tdb[(size_t)row * D_K + ln + 32 * i]; s += x * x; }
#pragma unroll
  for (int off = 16; off >= 1; off >>= 1) s += __shfl_xor(s, off);
  if (ln == 0) tq[row] = 0.5f * s;
}

// ---------- prep: T fragment blobs (hi/lo fp16 split). chunk = p*1024 + c*128 + hl*64 + l
__global__ void k_prep_t(const float* __restrict__ tdb, u16* __restrict__ pkT) {
  int ti = blockIdx.x;
  int t = threadIdx.x;
#pragma unroll
  for (int i = 0; i < 8; i++) {
    int ck = t + 256 * i;
    int l = ck & 63, hl = (ck >> 6) & 1, c = (ck >> 7) & 7, p = (ck >> 10) & 1;
    int row = ti * 32 + p * 16 + (l & 15);
    int k0 = c * 32 + ((l >> 4) & 3) * 8;
    const float* src = tdb + (size_t)row * D_K + k0;
    f16x8 o;
#pragma unroll
    for (int e = 0; e < 8; e++) {
      float v = src[e];
      f16 h = (f16)v;
      o[e] = hl ? (f16)(v - (float)h) : h;
    }
    *(f16x8*)(pkT + (size_t)ti * 16384 + ck * 8) = o;   // 32KB per tile
  }
}

// ---------- prep: V^T paired A-frag blobs (16x16x16). slot = p*512 + c*64 + l:
// lane l elem e -> V[ti*32 + p*16 + ((l>>4)&3)*4 + (e&3)][c*32 + (e>>2)*16 + (l&15)]
__global__ void k_prep_v(const float* __restrict__ src, u16* __restrict__ pkV) {
  int ti = blockIdx.x;   // M_DB/32 tiles
  int t = threadIdx.x;   // 256
#pragma unroll
  for (int i = 0; i < 4; i++) {
    int slot = t + 256 * i;
    int l = slot & 63, c = (slot >> 6) & 7, p = slot >> 9;
    int mbase = ti * 32 + p * 16 + ((l >> 4) & 3) * 4;
    int dbase = c * 32 + (l & 15);
    f16x8 o;
#pragma unroll
    for (int e = 0; e < 8; e++)
      o[e] = (f16)src[(size_t)(mbase + (e & 3)) * D_K + dbase + (e >> 2) * 16];
    *(f16x8*)(pkV + (size_t)ti * 8192 + slot * 8) = o;   // 16KB per tile
  }
}

// ---------- main flash kernel ----------
__launch_bounds__(512, 2)
__global__ void k_main(const u16* __restrict__ qpk, const u16* __restrict__ pkT,
                       const u16* __restrict__ pkV, const float* __restrict__ tq,
                       const float* __restrict__ stdv,
                       u16* __restrict__ pO, float* __restrict__ pm, float* __restrict__ pl)
{
  __shared__ __align__(16) char su[3][49152];   // [T 32KB | V^T 16KB] x3 rotating

  const int bid = blockIdx.x, chunk = bid & 7, qblk = bid >> 3;
  const int tid = threadIdx.x;
  const int w = tid >> 6, l = tid & 63;
  const int qg = w >> 1, p = w & 1;
  const int lq = l & 15, mg = (l >> 4) & 3;

  float is2l[2];
#pragma unroll
  for (int f = 0; f < 2; f++) {
    float sd = stdv[qblk * BQ + f * 64 + qg * 16 + lq];
    is2l[f] = LOG2E / (sd * sd);
  }

  // 2 Q fragment sets in registers (64 VGPRs)
  f16x8 qf[2][NCH];
#pragma unroll
  for (int f = 0; f < 2; f++) {
    const u16* qb = qpk + (size_t)(qblk * 8 + f * 4 + qg) * 4096 + l * 8;
#pragma unroll
    for (int c = 0; c < NCH; c++) qf[f][c] = *(const f16x8*)(qb + c * 512);
  }

  f32x4 acc[2][16];   // O^T partials over this wave's own m-half (full d)
#pragma unroll
  for (int f = 0; f < 2; f++)
#pragma unroll
    for (int dc = 0; dc < 16; dc++) acc[f][dc] = (f32x4){0.f, 0.f, 0.f, 0.f};
  float mrun[2] = {-3.0e38f, -3.0e38f}, lrun[2] = {0.f, 0.f};

  const size_t tbase = (size_t)chunk * NTILE;

  auto stage = [&](int t, int buf) {
    const char* gT = (const char*)pkT + (tbase + t) * 32768;
    const char* gV = (const char*)pkV + (tbase + t) * 16384;
    char* sb = &su[buf][0];
#pragma unroll
    for (int i = 0; i < 4; i++) gload16(gT + i * 8192 + tid * 16, sb + i * 8192 + w * 1024);
#pragma unroll
    for (int i = 0; i < 2; i++) gload16(gV + i * 8192 + tid * 16, sb + 32768 + i * 8192 + w * 1024);
  };

  // prologue: stage tiles 0 and 1; wait only for tile 0 (6 newest = tile 1)
  stage(0, 0);
  stage(1, 1);
  asm volatile("s_waitcnt vmcnt(6)" ::: "memory");
  __builtin_amdgcn_s_barrier();

  int cur = 0;
  for (int t = 0; t < NTILE; ++t) {
    // per-lane t_sq bias for this wave's 16 m-rows (issued BEFORE stage so its
    // wait doesn't drain the prefetch queue)
    const f32x4 t4 = *(const f32x4*)(tq + chunk * MC + t * BM + p * 16 + mg * 4);
    if (t + 2 < NTILE) { int nb = cur + 2; if (nb >= 3) nb -= 3; stage(t + 2, nb); }

    // ---- QK^T swapped: A=T (own m-half 16), B=Q regs -> D[m][q]; 4 indep chains ----
    f32x4 s0H = {0.f,0.f,0.f,0.f}, s0L = {0.f,0.f,0.f,0.f};
    f32x4 s1H = {0.f,0.f,0.f,0.f}, s1L = {0.f,0.f,0.f,0.f};
    const char* tb = &su[0][0] + cur * 49152 + p * 16384 + l * 16;
    __builtin_amdgcn_s_setprio(1);
#pragma unroll
    for (int c = 0; c < NCH; c++) {
      f16x8 aH = *(const f16x8*)(tb + c * 2048);
      f16x8 aL = *(const f16x8*)(tb + c * 2048 + 1024);
      s0H = __builtin_amdgcn_mfma_f32_16x16x32_f16(aH, qf[0][c], s0H, 0, 0, 0);
      s1H = __builtin_amdgcn_mfma_f32_16x16x32_f16(aH, qf[1][c], s1H, 0, 0, 0);
      s0L = __builtin_amdgcn_mfma_f32_16x16x32_f16(aL, qf[0][c], s0L, 0, 0, 0);
      s1L = __builtin_amdgcn_mfma_f32_16x16x32_f16(aL, qf[1][c], s1L, 0, 0, 0);
    }
    __builtin_amdgcn_s_setprio(0);

    float l20[4], l21[4];
#pragma unroll
    for (int r = 0; r < 4; r++) {
      l20[r] = (s0H[r] + s0L[r] - t4[r]) * is2l[0];
      l21[r] = (s1H[r] + s1L[r] - t4[r]) * is2l[1];
    }
    // in-wave softmax over this wave's own 16 m (4 regs + mg-lanes at xor 16,32)
    float px0 = fmaxf(fmaxf(l20[0], l20[1]), fmaxf(l20[2], l20[3]));
    float px1 = fmaxf(fmaxf(l21[0], l21[1]), fmaxf(l21[2], l21[3]));
    px0 = fmaxf(px0, __shfl_xor(px0, 16)); px0 = fmaxf(px0, __shfl_xor(px0, 32));
    px1 = fmaxf(px1, __shfl_xor(px1, 16)); px1 = fmaxf(px1, __shfl_xor(px1, 32));
    const float mnew0 = fmaxf(mrun[0], px0);
    const float mnew1 = fmaxf(mrun[1], px1);
    if (__any((mnew0 > mrun[0]) | (mnew1 > mrun[1]))) {   // exact-skip rescale
      const float cl0 = exp2f(mrun[0] - mnew0);
      const float cl1 = exp2f(mrun[1] - mnew1);
      mrun[0] = mnew0; mrun[1] = mnew1;
      lrun[0] *= cl0;  lrun[1] *= cl1;
#pragma unroll
      for (int dc = 0; dc < 16; dc++) {
#pragma unroll
        for (int r = 0; r < 4; r++) { acc[0][dc][r] *= cl0; acc[1][dc][r] *= cl1; }
      }
    }
    float pr0[4], pr1[4], ls0 = 0.f, ls1 = 0.f;
#pragma unroll
    for (int r = 0; r < 4; r++) {
      pr0[r] = exp2f(l20[r] - mrun[0]); ls0 += pr0[r];
      pr1[r] = exp2f(l21[r] - mrun[1]); ls1 += pr1[r];
    }
    ls0 += __shfl_xor(ls0, 16); ls0 += __shfl_xor(ls0, 32);
    ls1 += __shfl_xor(ls1, 16); ls1 += __shfl_xor(ls1, 32);
    lrun[0] += ls0; lrun[1] += ls1;

    // P as B-operand fragments straight from registers (K=16 = own m-half)
    f16x4v pf0, pf1;
#pragma unroll
    for (int r = 0; r < 4; r++) { pf0[r] = (f16)pr0[r]; pf1[r] = (f16)pr1[r]; }

    // ---- PV swapped: acc[f][dc] += V^T_frag(dc) * pf[f] ----
    const char* vb = &su[0][0] + cur * 49152 + 32768 + p * 8192 + l * 16;
    __builtin_amdgcn_s_setprio(1);
#pragma unroll
    for (int c = 0; c < 8; c++) {
      f16x8 vv = *(const f16x8*)(vb + c * 1024);
      f16x4v a0 = __builtin_shufflevector(vv, vv, 0, 1, 2, 3);
      f16x4v a1 = __builtin_shufflevector(vv, vv, 4, 5, 6, 7);
      acc[0][2 * c]     = __builtin_amdgcn_mfma_f32_16x16x16f16(a0, pf0, acc[0][2 * c], 0, 0, 0);
      acc[1][2 * c]     = __builtin_amdgcn_mfma_f32_16x16x16f16(a0, pf1, acc[1][2 * c], 0, 0, 0);
      acc[0][2 * c + 1] = __builtin_amdgcn_mfma_f32_16x16x16f16(a1, pf0, acc[0][2 * c + 1], 0, 0, 0);
      acc[1][2 * c + 1] = __builtin_amdgcn_mfma_f32_16x16x16f16(a1, pf1, acc[1][2 * c + 1], 0, 0, 0);
    }
    __builtin_amdgcn_s_setprio(0);

    // ---- single end-of-tile barrier: next tile staged (counted, never drain-0) ----
    if (t < NTILE - 1) {
      if (t < NTILE - 2) asm volatile("s_waitcnt vmcnt(6)" ::: "memory");
      else               asm volatile("s_waitcnt vmcnt(0)" ::: "memory");
      __builtin_amdgcn_s_barrier();
    }
    cur = (cur == 2) ? 0 : cur + 1;
  }

  // ---- epilogue: each wave writes its OWN chunk partials (f16), no reduce ----
  const int ce = chunk * 2 + p;
#pragma unroll
  for (int f = 0; f < 2; f++) {
    const int row = qblk * BQ + f * 64 + qg * 16 + lq;
#pragma unroll
    for (int dc = 0; dc < 16; dc++) {
      f16x4v o4;
#pragma unroll
      for (int r = 0; r < 4; r++) o4[r] = (f16)acc[f][dc][r];
      *(f16x4v*)(pO + ((size_t)ce * N_Q + row) * D_K + dc * 16 + mg * 4) = o4;
    }
    if (mg == 0) {
      pm[(size_t)ce * N_Q + row] = mrun[f];
      pl[(size_t)ce * N_Q + row] = lrun[f];
    }
  }
}

// ---------- combine chunk partials ----------
__global__ void k_combine(const u16* __restrict__ pO, const float* __restrict__ pm,
                          const float* __restrict__ pl, float* __restrict__ out)
{
  int n = blockIdx.x, d = threadIdx.x;
  float M = -3.0e38f;
#pragma unroll
  for (int c = 0; c < NCHE; c++) M = fmaxf(M, pm[(size_t)c * N_Q + n]);
  float den = 0.f, num = 0.f;
#pragma unroll
  for (int c = 0; c < NCHE; c++) {
    float w = exp2f(pm[(size_t)c * N_Q + n] - M);
    den += w * pl[(size_t)c * N_Q + n];
    float v = (float)(*(const f16*)(pO + ((size_t)c * N_Q + n) * D_K + d));
    num += w * v;
  }
  out[(size_t)n * D_K + d] = num / den;
}

extern "C" void kernel_launch(void* const* d_in, const int* in_sizes, int n_in,
                              void* d_out, int out_size, void* d_ws, size_t ws_size,
                              hipStream_t stream)
{
  const float* q    = (const float*)d_in[0];
  const float* stdv = (const float*)d_in[1];
  const float* src  = (const float*)d_in[2];   // source_db (V)
  const float* tdb  = (const float*)d_in[3];   // target_db (T)
  float* out = (float*)d_out;

  char* wsp = (char*)d_ws;
  u16* qpk = (u16*)wsp;   wsp += (size_t)N_Q * D_K * 2;            // 2 MB
  u16* pkT = (u16*)wsp;   wsp += (size_t)M_DB * D_K * 2 * 2;       // 16.8 MB (hi+lo)
  u16* pkV = (u16*)wsp;   wsp += (size_t)M_DB * D_K * 2;           // 8.4 MB
  float* tq = (float*)wsp; wsp += (size_t)M_DB * 4;                // 64 KB
  u16* pO = (u16*)wsp;    wsp += (size_t)NCHE * N_Q * D_K * 2;     // 33.5 MB (f16)
  float* pm = (float*)wsp; wsp += (size_t)NCHE * N_Q * 4;
  float* pl = (float*)wsp; wsp += (size_t)NCHE * N_Q * 4;

  hipLaunchKernelGGL(k_prep_q,  dim3(N_Q / 16), dim3(256), 0, stream, q, qpk);
  hipLaunchKernelGGL(k_prep_tq, dim3(M_DB / 8), dim3(256), 0, stream, tdb, tq);
  hipLaunchKernelGGL(k_prep_t,  dim3(M_DB / 32), dim3(256), 0, stream, tdb, pkT);
  hipLaunchKernelGGL(k_prep_v,  dim3(M_DB / 32), dim3(256), 0, stream, src, pkV);
  hipLaunchKernelGGL(k_main,    dim3(32 * NCHUNK), dim3(512), 0, stream,
                     qpk, pkT, pkV, tq, stdv, pO, pm, pl);
  hipLaunchKernelGGL(k_combine, dim3(N_Q), dim3(256), 0, stream, pO, pm, pl, out);
}